// Round 13
// baseline (154.625 us; speedup 1.0000x reference)
//
#include <hip/hip_runtime.h>
#include <math.h>

#define B_ 2
#define N_ 6
#define D_ 59
#define FH 32
#define FW 88
#define C_ 80
#define NX 360
#define NY 360
#define P_PER_B (N_*D_*FH*FW)     // 996,864
#define NPTS (B_*P_PER_B)         // 1,993,728
#define NT4 (NPTS/4)              // 498,432 geom threads (= 1947*256)
#define NCELL (NX*NY)             // 129,600
#define NC (B_*NCELL)             // 259,200 cells
#define NBLK 254
#define NCP (NBLK*1024)           // 260,096
#define OUT4 (B_*C_*NCELL/4)      // 5,184,000 float4 in out
#define SMAX 32                   // cells <= SMAX points -> thread-mode
#define CHK 96                    // points per wave-chunk (divisible by 3)
#define MAXCHK (NC/4 + NPTS/CHK)
#define TOTBLK 2048
#define NWAVES (TOTBLK*256/64)    // 8192

// Static device scratch. Self-cleaning invariant: g_cnt/g_nR (alloc cleans)
// and g_nS/g_nB/g_total (fill cleans) are zero at every launch entry (BSS
// zero-init covers launch #1). Everything else is written before read.
__device__ __align__(16) int g_cnt[NCP];
__device__ int   g_cur[NC];
__device__ __align__(16) int g_plist[NPTS];
__device__ int2  g_runs[NPTS];     // {cell | len<<18, p_start}
__device__ int   g_nR, g_nR2;
__device__ int   g_total;
__device__ int   g_nS, g_nB;       // appended by alloc; zeroed by fill
__device__ int   g_nS2, g_nB2;     // snapshots read by gather
__device__ int2  g_cellS[NC];      // {cell | len<<18, o0}
__device__ int2  g_chunkB[MAXCHK]; // {cell | clen<<18 | sole<<30, s0}

// ---- 1) geom: 4 points/thread, fused out-zero + per-block inverse,
//         emits per-cell counts + compact run list (no g_code array).
__global__ void k_geomz(const float* __restrict__ itrans,
                        const float* __restrict__ iscale,
                        const float* __restrict__ l2i,
                        float* __restrict__ out) {
#pragma clang fp contract(off)
  __shared__ float sinv[B_*N_*16];
  int tid = threadIdx.x;
  int gid = blockIdx.x*256 + tid;                  // grid exact: NT4/256 = 1947

  // out-zero (fire-and-forget; overlaps inverse + geom below)
  const float4 z4 = make_float4(0.f,0.f,0.f,0.f);
  #pragma unroll
  for (int u4=0; u4<11; ++u4) {
    int u = gid + u4*NT4;
    if (u < OUT4) ((float4*)out)[u] = z4;
  }

  // per-block redundant inverse of the 12 lidar2img matrices (f64 GJ, pivot)
  if (tid < B_*N_) {
    int m = tid;
    double a[4][4], inv[4][4];
    for (int r=0;r<4;r++) for (int j=0;j<4;j++){
      a[r][j] = (double)l2i[m*16+r*4+j];
      inv[r][j] = (r==j)?1.0:0.0;
    }
    for (int k=0;k<4;k++){
      int pv=k; double mx=fabs(a[k][k]);
      for (int r=k+1;r<4;r++){ double v=fabs(a[r][k]); if (v>mx){mx=v;pv=r;} }
      if (pv!=k){
        for (int j=0;j<4;j++){
          double t=a[k][j]; a[k][j]=a[pv][j]; a[pv][j]=t;
          t=inv[k][j]; inv[k][j]=inv[pv][j]; inv[pv][j]=t;
        }
      }
      double pi = 1.0/a[k][k];
      for (int j=0;j<4;j++){ a[k][j]*=pi; inv[k][j]*=pi; }
      for (int r=0;r<4;r++) if (r!=k){
        double f=a[r][k];
        for (int j=0;j<4;j++){ a[r][j]-=f*a[k][j]; inv[r][j]-=f*inv[k][j]; }
      }
    }
    for (int r=0;r<4;r++) for (int j=0;j<4;j++)
      sinv[m*16+r*4+j] = (float)inv[r][j];
  }
  __syncthreads();

  // decompose base point (4-aligned; w-chunk never crosses a row: 88 = 4*22)
  int p0 = gid*4;
  int b  = p0 / P_PER_B;
  int r  = p0 - b*P_PER_B;
  int n  = r / (D_*FH*FW);
  int r2 = r - n*(D_*FH*FW);
  int d  = r2 / (FH*FW);
  int r3 = r2 - d*(FH*FW);
  int h  = r3 / FW;
  int w0 = r3 - h*FW;
  int bn = b*N_ + n;

  float yh = (float)((double)h * (255.0/31.0));    // np.linspace f64, rounded
  float dd = (float)(d + 1);                       // ds = 1..59

  float t0 = itrans[bn*3+0], t1 = itrans[bn*3+1], t2 = itrans[bn*3+2];
  float sc = iscale[bn];

  float py = yh + t1, pd = dd + t2;
  float x1 = py / sc;
  float p1v = x1*pd, p2v = pd;

  const float* iv = &sinv[bn*16];
  // shared exact products (same bits as per-point evaluation)
  float m1x = iv[1]*p1v, m2x = iv[2]*p2v;
  float m1y = iv[5]*p1v, m2y = iv[6]*p2v;
  float m1z = iv[9]*p1v, m2z = iv[10]*p2v;

  int c[4];
  #pragma unroll
  for (int k=0; k<4; ++k) {
    float xw = (float)((double)(w0+k) * (703.0/87.0));
    float px = xw + t0;
    float x0 = px / sc;
    float p0v = x0*pd;
    float gx = ((iv[0]*p0v + m1x) + m2x) + iv[3]*1.0f;
    float gy = ((iv[4]*p0v + m1y) + m2y) + iv[7]*1.0f;
    float gz = ((iv[8]*p0v + m1z) + m2z) + iv[11]*1.0f;
    int vx = (int)((gx + 54.0f) / 0.3f);           // trunc == astype(int32)
    int vy = (int)((gy + 54.0f) / 0.3f);
    int vz = (int)((gz + 10.0f) / 20.0f);
    bool ok = (vx>=0) & (vx<NX) & (vy>=0) & (vy<NY) & (vz>=0) & (vz<1);
    c[k] = ok ? (b*NCELL + vx*NY + vy) : -1;
  }

  // thread-local run extraction (<=4 runs) + per-cell count atomics
  int2 runs[4];
  int rc = 0;
  {
    int cur = c[0], st = 0;
    #pragma unroll
    for (int k=1; k<4; ++k) {
      if (c[k] != cur) {
        if (cur >= 0) runs[rc++] = make_int2(cur | ((k-st) << 18), p0 + st);
        cur = c[k]; st = k;
      }
    }
    if (cur >= 0) runs[rc++] = make_int2(cur | ((4-st) << 18), p0 + st);
  }
  for (int k=0; k<rc; ++k)
    atomicAdd(&g_cnt[runs[k].x & 0x3FFFF], (runs[k].x >> 18) & 7);

  // wave-aggregated append to the run list
  int lane = tid & 63;
  int pre = rc;
  #pragma unroll
  for (int off=1; off<64; off<<=1) {
    int x = __shfl_up(pre, off);
    if (lane >= off) pre += x;
  }
  int wtot = __shfl(pre, 63);
  int wbase = 0;
  if (lane == 63 && wtot > 0) wbase = atomicAdd(&g_nR, wtot);
  wbase = __shfl(wbase, 63);
  int myb = wbase + pre - rc;
  for (int k=0; k<rc; ++k) g_runs[myb + k] = runs[k];
}

// ---- 2) unordered segment allocation + classification; cleans cnt/nR
__global__ void __launch_bounds__(1024) k_alloc() {
  int t = threadIdx.x, bid = blockIdx.x;
  int i = bid*1024 + t;
  if (bid == 0 && t == 0) { g_nR2 = g_nR; g_nR = 0; }
  bool inb = (i < NC);
  int len = inb ? g_cnt[i] : 0;
  if (inb && len) g_cnt[i] = 0;                    // self-clean for next launch
  int lane = t & 63;

  int pre = len;                                   // wave-inclusive prefix
  #pragma unroll
  for (int off=1; off<64; off<<=1) {
    int x = __shfl_up(pre, off);
    if (lane >= off) pre += x;
  }
  int wtot = __shfl(pre, 63);
  int wbase = 0;
  if (lane == 63 && wtot > 0) wbase = atomicAdd(&g_total, wtot);
  wbase = __shfl(wbase, 63);
  int base = wbase + pre - len;                    // exclusive within wave
  if (inb && len > 0) g_cur[i] = base;

  bool isS = inb && (len > 0) && (len <= SMAX);
  unsigned long long m = __ballot(isS);
  if (m) {
    int ldr = __ffsll((long long)m) - 1;
    int cbase = 0;
    if (lane == ldr) cbase = atomicAdd(&g_nS, (int)__popcll(m));
    cbase = __shfl(cbase, ldr);
    if (isS) {
      int rank = __popcll(m & ((1ULL << lane) - 1ULL));
      g_cellS[cbase + rank] = make_int2(i | (len << 18), base);
    }
  }
  if (inb && len > SMAX) {
    int nch = (len + CHK - 1) / CHK;
    int cb = atomicAdd(&g_nB, nch);
    int sole = (nch == 1) ? 1 : 0;
    for (int k = 0; k < nch; ++k) {
      int clen = min(CHK, len - k*CHK);
      g_chunkB[cb + k] = make_int2(i | (clen << 18) | (sole << 30), base + k*CHK);
    }
  }
}

// ---- 3) fill: expand runs into the cell-grouped point list; clean counters
__global__ void k_fill() {
  int gid = blockIdx.x*256 + threadIdx.x;
  if (gid == 0) { g_nS2 = g_nS; g_nB2 = g_nB; g_nS = 0; g_nB = 0; g_total = 0; }
  int nR = g_nR2;
  for (int i = gid; i < nR; i += 256*256) {
    int2 e = g_runs[i];
    int cell = e.x & 0x3FFFF;
    int len  = (e.x >> 18) & 7;                    // 1..4
    int pos = atomicAdd(&g_cur[cell], len);
    #pragma unroll
    for (int k=0; k<4; ++k)
      if (k < len) g_plist[pos + k] = e.y + k;
  }
}

// ---- 4) gather, unified: ALL 8192 waves grid-stride the chunk list
// (wave-mode), then fall through to small-cell items (thread-mode).
__global__ void __launch_bounds__(256) k_gather(const float* __restrict__ feats,
                                                float* __restrict__ out) {
  const float4* f4 = (const float4*)feats;
  int gtid = blockIdx.x*256 + threadIdx.x;
  int lane = threadIdx.x & 63;

  // ---- wave-mode: one 64-lane wave per <=CHK chunk (3 pts x 20 ch-groups)
  {
    int nB = g_nB2;
    int wid = gtid >> 6;
    int grp = lane/20;
    int c4 = lane - grp*20;
    bool act = lane < 60;
    for (int it = wid; it < nB; it += NWAVES) {
      int2 e = g_chunkB[it];
      int c    = e.x & 0x3FFFF;
      int clen = (e.x >> 18) & 0x7F;
      int sole = (e.x >> 30) & 1;
      int s0 = e.y;
      int s1 = s0 + clen;
      float ax=0.f, ay=0.f, az=0.f, aw=0.f;
      if (act) {
        #pragma unroll 1
        for (int rr=0; rr<4; ++rr) {               // 4 rounds x 8-deep, branch-free
          int j0 = s0 + grp + 24*rr;
          if (j0 >= s1) break;
          int p[8];
          #pragma unroll
          for (int k=0;k<8;++k) p[k] = g_plist[min(j0 + 3*k, NPTS-1)];
          float4 v[8];
          #pragma unroll
          for (int k=0;k<8;++k) v[k] = f4[(size_t)min(max(p[k],0),NPTS-1)*20 + c4];
          #pragma unroll
          for (int k=0;k<8;++k) {
            float sel = (j0 + 3*k < s1) ? 1.f : 0.f;   // exact: adds 0.0 terms
            ax = fmaf(sel, v[k].x, ax);
            ay = fmaf(sel, v[k].y, ay);
            az = fmaf(sel, v[k].z, az);
            aw = fmaf(sel, v[k].w, aw);
          }
        }
      }
      float bx=__shfl(ax,c4+20), by=__shfl(ay,c4+20), bz=__shfl(az,c4+20), bw=__shfl(aw,c4+20);
      float cx=__shfl(ax,c4+40), cy=__shfl(ay,c4+40), cz=__shfl(az,c4+40), cw=__shfl(aw,c4+40);
      if (lane < 20) {
        ax += bx + cx; ay += by + cy; az += bz + cz; aw += bw + cw;
        int b = c / NCELL;
        int xy = c - b*NCELL;
        float* dst = out + (size_t)(b*C_ + c4*4)*NCELL + xy;
        if (sole) {
          dst[0]       = ax;
          dst[NCELL]   = ay;
          dst[2*NCELL] = az;
          dst[3*NCELL] = aw;
        } else {                                   // dst zeroed by k_geomz
          atomicAdd(dst,         ax);
          atomicAdd(dst+NCELL,   ay);
          atomicAdd(dst+2*NCELL, az);
          atomicAdd(dst+3*NCELL, aw);
        }
      }
    }
  }

  // ---- thread-mode: thread per (small cell, c4); branch-free 8-batches
  {
    int nS = g_nS2;
    int tot = nS*20;
    for (int i = gtid; i < tot; i += TOTBLK*256) {
      int ci = i/20;
      int c4 = i - ci*20;
      int2 e = g_cellS[ci];
      int c   = e.x & 0x3FFFF;
      int len = (e.x >> 18) & 0x7F;                // 1..SMAX
      int o0  = e.y;
      float ax=0.f, ay=0.f, az=0.f, aw=0.f;
      int nb = (len + 7) >> 3;                     // 1..4 batches
      for (int bi = 0; bi < nb; ++bi) {
        int base = o0 + bi*8;
        int rem = len - bi*8;                      // >0
        int p[8];
        #pragma unroll
        for (int k=0;k<8;++k) p[k] = g_plist[min(base+k, NPTS-1)];
        float4 v[8];
        #pragma unroll
        for (int k=0;k<8;++k) {
          int q = min(max(p[k],0), NPTS-1);        // clamp stale tails in-bounds
          v[k] = f4[(size_t)q*20 + c4];
        }
        #pragma unroll
        for (int k=0;k<8;++k) {
          float sel = (k < rem) ? 1.f : 0.f;       // exact: adds 0.0 terms
          ax = fmaf(sel, v[k].x, ax);
          ay = fmaf(sel, v[k].y, ay);
          az = fmaf(sel, v[k].z, az);
          aw = fmaf(sel, v[k].w, aw);
        }
      }
      int b = c / NCELL;
      int xy = c - b*NCELL;
      float* dst = out + (size_t)(b*C_ + c4*4)*NCELL + xy;
      dst[0]       = ax;
      dst[NCELL]   = ay;
      dst[2*NCELL] = az;
      dst[3*NCELL] = aw;
    }
  }
}

extern "C" void kernel_launch(void* const* d_in, const int* in_sizes, int n_in,
                              void* d_out, int out_size, void* d_ws, size_t ws_size,
                              hipStream_t stream) {
  const float* feats  = (const float*)d_in[0];
  const float* itrans = (const float*)d_in[1];
  const float* iscale = (const float*)d_in[2];
  const float* l2i    = (const float*)d_in[3];
  float* out = (float*)d_out;

  k_geomz<<<NT4/256, 256, 0, stream>>>(itrans, iscale, l2i, out);  // 1,947 blocks
  k_alloc<<<NBLK, 1024, 0, stream>>>();                            // 254 blocks
  k_fill<<<256, 256, 0, stream>>>();                               // 256 blocks
  k_gather<<<TOTBLK, 256, 0, stream>>>(feats, out);                // 2,048 blocks
}

// Round 14
// 127.026 us; speedup vs baseline: 1.2173x; 1.2173x over previous
//
#include <hip/hip_runtime.h>
#include <math.h>

#define B_ 2
#define N_ 6
#define D_ 59
#define FH 32
#define FW 88
#define C_ 80
#define NX 360
#define NY 360
#define P_PER_B (N_*D_*FH*FW)     // 996,864
#define NPTS (B_*P_PER_B)         // 1,993,728 = 7788*256
#define NCELL (NX*NY)             // 129,600
#define NC (B_*NCELL)             // 259,200 cells
#define NBLK 254
#define NCP (NBLK*1024)           // 260,096
#define OUT4 (B_*C_*NCELL/4)      // 5,184,000 float4 in out
#define SMAX 32                   // cells <= SMAX points -> thread-mode
#define CHK 96                    // points per wave-chunk (divisible by 3)
#define MAXCHK (NC/4 + NPTS/CHK)
#define TOTBLK 2048
#define NWAVES (TOTBLK*256/64)    // 8192

// Static device scratch. Self-cleaning invariant: g_cnt/g_nS/g_nB/g_total are
// zero at every launch entry (BSS zero-init for launch #1; k_alloc re-zeroes
// cnt after its last read, k_fill re-zeroes the counters after snapshot).
__device__ int   g_code[NPTS];
__device__ __align__(16) int g_cnt[NCP];
__device__ int   g_cur[NC];
__device__ __align__(16) int g_plist[NPTS];
__device__ int   g_total;
__device__ int   g_nS, g_nB;       // appended by alloc; zeroed by fill
__device__ int   g_nS2, g_nB2;     // snapshots read by gather
__device__ int2  g_cellS[NC];      // {cell | len<<18, o0}
__device__ int2  g_chunkB[MAXCHK]; // {cell | clen<<18 | sole<<30, s0}

// ---- 1) geom fused with out-zero + per-block redundant matrix inverse
__global__ void k_geomz(const float* __restrict__ itrans,
                        const float* __restrict__ iscale,
                        const float* __restrict__ l2i,
                        float* __restrict__ out) {
#pragma clang fp contract(off)
  __shared__ float sinv[B_*N_*16];
  int tid = threadIdx.x;
  int p = blockIdx.x*256 + tid;                    // grid exact: NPTS/256

  // out-zero (fire-and-forget stores; overlap the inverse + geom below)
  const float4 z4 = make_float4(0.f,0.f,0.f,0.f);
  ((float4*)out)[p] = z4;
  ((float4*)out)[p + NPTS] = z4;
  {
    int u = p + 2*NPTS;
    if (u < OUT4) ((float4*)out)[u] = z4;
  }

  // per-block redundant inverse of the 12 lidar2img matrices (f64 GJ, pivot)
  if (tid < B_*N_) {
    int m = tid;
    double a[4][4], inv[4][4];
    for (int r=0;r<4;r++) for (int j=0;j<4;j++){
      a[r][j] = (double)l2i[m*16+r*4+j];
      inv[r][j] = (r==j)?1.0:0.0;
    }
    for (int k=0;k<4;k++){
      int pv=k; double mx=fabs(a[k][k]);
      for (int r=k+1;r<4;r++){ double v=fabs(a[r][k]); if (v>mx){mx=v;pv=r;} }
      if (pv!=k){
        for (int j=0;j<4;j++){
          double t=a[k][j]; a[k][j]=a[pv][j]; a[pv][j]=t;
          t=inv[k][j]; inv[k][j]=inv[pv][j]; inv[pv][j]=t;
        }
      }
      double pi = 1.0/a[k][k];
      for (int j=0;j<4;j++){ a[k][j]*=pi; inv[k][j]*=pi; }
      for (int r=0;r<4;r++) if (r!=k){
        double f=a[r][k];
        for (int j=0;j<4;j++){ a[r][j]-=f*a[k][j]; inv[r][j]-=f*inv[k][j]; }
      }
    }
    for (int r=0;r<4;r++) for (int j=0;j<4;j++)
      sinv[m*16+r*4+j] = (float)inv[r][j];
  }
  __syncthreads();

  // geometry (identical math to R8/R10/R11; iv from LDS)
  int b  = p / P_PER_B;
  int r  = p - b*P_PER_B;
  int n  = r / (D_*FH*FW);
  int r2 = r - n*(D_*FH*FW);
  int d  = r2 / (FH*FW);
  int r3 = r2 - d*(FH*FW);
  int h  = r3 / FW;
  int w  = r3 - h*FW;
  int bn = b*N_ + n;

  float xw = (float)((double)w * (703.0/87.0));    // np.linspace in f64, rounded
  float yh = (float)((double)h * (255.0/31.0));
  float dd = (float)(d + 1);                       // ds = 1..59

  float t0 = itrans[bn*3+0], t1 = itrans[bn*3+1], t2 = itrans[bn*3+2];
  float s  = iscale[bn];

  float px = xw + t0, py = yh + t1, pd = dd + t2;
  float x0 = px / s, x1 = py / s;
  float p0 = x0*pd, p1 = x1*pd, p2 = pd;

  const float* iv = &sinv[bn*16];
  float gx = ((iv[0]*p0 + iv[1]*p1) + iv[2]*p2)  + iv[3]*1.0f;
  float gy = ((iv[4]*p0 + iv[5]*p1) + iv[6]*p2)  + iv[7]*1.0f;
  float gz = ((iv[8]*p0 + iv[9]*p1) + iv[10]*p2) + iv[11]*1.0f;

  int vx = (int)((gx + 54.0f) / 0.3f);             // trunc == astype(int32)
  int vy = (int)((gy + 54.0f) / 0.3f);
  int vz = (int)((gz + 10.0f) / 20.0f);

  bool ok = (vx>=0) & (vx<NX) & (vy>=0) & (vy<NY) & (vz>=0) & (vz<1);
  int code = ok ? (b*NCELL + vx*NY + vy) : -1;
  g_code[p] = code;

  int lane = tid & 63;
  int prev = __shfl_up(code, 1);
  bool leader = (lane == 0) || (code != prev);
  unsigned long long m = __ballot(leader);
  if (leader && code >= 0) {
    unsigned long long above = (lane < 63) ? (m >> (lane+1)) : 0ULL;
    int len = above ? __ffsll(above) : (64 - lane);
    atomicAdd(&g_cnt[code], len);
  }
}

// ---- 2) unordered segment allocation + classification; self-cleans cnt
__global__ void __launch_bounds__(1024) k_alloc() {
  int t = threadIdx.x, bid = blockIdx.x;
  int i = bid*1024 + t;
  bool inb = (i < NC);
  int len = inb ? g_cnt[i] : 0;
  if (inb && len) g_cnt[i] = 0;                    // self-clean for next launch
  int lane = t & 63;

  int pre = len;                                   // wave-inclusive prefix
  #pragma unroll
  for (int off=1; off<64; off<<=1) {
    int x = __shfl_up(pre, off);
    if (lane >= off) pre += x;
  }
  int wtot = __shfl(pre, 63);
  int wbase = 0;
  if (lane == 63 && wtot > 0) wbase = atomicAdd(&g_total, wtot);
  wbase = __shfl(wbase, 63);
  int base = wbase + pre - len;                    // exclusive within wave
  if (inb && len > 0) g_cur[i] = base;

  bool isS = inb && (len > 0) && (len <= SMAX);
  unsigned long long m = __ballot(isS);
  if (m) {
    int ldr = __ffsll((long long)m) - 1;
    int cbase = 0;
    if (lane == ldr) cbase = atomicAdd(&g_nS, (int)__popcll(m));
    cbase = __shfl(cbase, ldr);
    if (isS) {
      int rank = __popcll(m & ((1ULL << lane) - 1ULL));
      g_cellS[cbase + rank] = make_int2(i | (len << 18), base);
    }
  }
  if (inb && len > SMAX) {
    int nch = (len + CHK - 1) / CHK;
    int cb = atomicAdd(&g_nB, nch);
    int sole = (nch == 1) ? 1 : 0;
    for (int k = 0; k < nch; ++k) {
      int clen = min(CHK, len - k*CHK);
      g_chunkB[cb + k] = make_int2(i | (clen << 18) | (sole << 30), base + k*CHK);
    }
  }
}

// ---- 3) fill cell-sorted point list + snapshot/clean counters
__global__ void k_fill() {
  int gid = blockIdx.x*256 + threadIdx.x;          // grid exact: NPTS/256
  if (gid == 0) { g_nS2 = g_nS; g_nB2 = g_nB; g_nS = 0; g_nB = 0; g_total = 0; }

  int code = g_code[gid];
  int lane = threadIdx.x & 63;
  int prev = __shfl_up(code, 1);
  bool leader = (lane == 0) || (code != prev);
  unsigned long long m = __ballot(leader);
  unsigned long long mask_le = (lane==63) ? ~0ULL : ((1ULL << (lane+1)) - 1ULL);
  int leaderLane = 63 - __clzll(m & mask_le);
  int pos0 = 0;
  if (leader && code >= 0) {
    unsigned long long above = (lane < 63) ? (m >> (lane+1)) : 0ULL;
    int len = above ? __ffsll(above) : (64 - lane);
    pos0 = atomicAdd(&g_cur[code], len);
  }
  pos0 = __shfl(pos0, leaderLane);
  if (code >= 0) g_plist[pos0 + (lane - leaderLane)] = gid;
}

// ---- 4) gather, unified: ALL 8192 waves grid-stride the chunk list
// (wave-mode), then fall through to small-cell items (thread-mode).
__global__ void __launch_bounds__(256) k_gather(const float* __restrict__ feats,
                                                float* __restrict__ out) {
  const float4* f4 = (const float4*)feats;
  int gtid = blockIdx.x*256 + threadIdx.x;
  int lane = threadIdx.x & 63;

  // ---- wave-mode: one 64-lane wave per <=CHK chunk (3 pts x 20 ch-groups)
  {
    int nB = g_nB2;
    int wid = gtid >> 6;
    int grp = lane/20;
    int c4 = lane - grp*20;
    bool act = lane < 60;
    for (int it = wid; it < nB; it += NWAVES) {
      int2 e = g_chunkB[it];
      int c    = e.x & 0x3FFFF;
      int clen = (e.x >> 18) & 0x7F;
      int sole = (e.x >> 30) & 1;
      int s0 = e.y;
      int s1 = s0 + clen;
      float ax=0.f, ay=0.f, az=0.f, aw=0.f;
      if (act) {
        #pragma unroll 1
        for (int rr=0; rr<4; ++rr) {               // 4 rounds x 8-deep, branch-free
          int j0 = s0 + grp + 24*rr;
          if (j0 >= s1) break;
          int p[8];
          #pragma unroll
          for (int k=0;k<8;++k) p[k] = g_plist[min(j0 + 3*k, NPTS-1)];
          float4 v[8];
          #pragma unroll
          for (int k=0;k<8;++k) v[k] = f4[(size_t)min(max(p[k],0),NPTS-1)*20 + c4];
          #pragma unroll
          for (int k=0;k<8;++k) {
            float sel = (j0 + 3*k < s1) ? 1.f : 0.f;   // exact: adds 0.0 terms
            ax = fmaf(sel, v[k].x, ax);
            ay = fmaf(sel, v[k].y, ay);
            az = fmaf(sel, v[k].z, az);
            aw = fmaf(sel, v[k].w, aw);
          }
        }
      }
      float bx=__shfl(ax,c4+20), by=__shfl(ay,c4+20), bz=__shfl(az,c4+20), bw=__shfl(aw,c4+20);
      float cx=__shfl(ax,c4+40), cy=__shfl(ay,c4+40), cz=__shfl(az,c4+40), cw=__shfl(aw,c4+40);
      if (lane < 20) {
        ax += bx + cx; ay += by + cy; az += bz + cz; aw += bw + cw;
        int b = c / NCELL;
        int xy = c - b*NCELL;
        float* dst = out + (size_t)(b*C_ + c4*4)*NCELL + xy;
        if (sole) {
          dst[0]       = ax;
          dst[NCELL]   = ay;
          dst[2*NCELL] = az;
          dst[3*NCELL] = aw;
        } else {                                   // dst zeroed by k_geomz
          atomicAdd(dst,         ax);
          atomicAdd(dst+NCELL,   ay);
          atomicAdd(dst+2*NCELL, az);
          atomicAdd(dst+3*NCELL, aw);
        }
      }
    }
  }

  // ---- thread-mode: thread per (small cell, c4); branch-free 8-batches
  {
    int nS = g_nS2;
    int tot = nS*20;
    for (int i = gtid; i < tot; i += TOTBLK*256) {
      int ci = i/20;
      int c4 = i - ci*20;
      int2 e = g_cellS[ci];
      int c   = e.x & 0x3FFFF;
      int len = (e.x >> 18) & 0x7F;                // 1..SMAX
      int o0  = e.y;
      float ax=0.f, ay=0.f, az=0.f, aw=0.f;
      int nb = (len + 7) >> 3;                     // 1..4 batches
      for (int bi = 0; bi < nb; ++bi) {
        int base = o0 + bi*8;
        int rem = len - bi*8;                      // >0
        int p[8];
        #pragma unroll
        for (int k=0;k<8;++k) p[k] = g_plist[min(base+k, NPTS-1)];
        float4 v[8];
        #pragma unroll
        for (int k=0;k<8;++k) {
          int q = min(max(p[k],0), NPTS-1);        // clamp stale tails in-bounds
          v[k] = f4[(size_t)q*20 + c4];
        }
        #pragma unroll
        for (int k=0;k<8;++k) {
          float sel = (k < rem) ? 1.f : 0.f;       // exact: adds 0.0 terms
          ax = fmaf(sel, v[k].x, ax);
          ay = fmaf(sel, v[k].y, ay);
          az = fmaf(sel, v[k].z, az);
          aw = fmaf(sel, v[k].w, aw);
        }
      }
      int b = c / NCELL;
      int xy = c - b*NCELL;
      float* dst = out + (size_t)(b*C_ + c4*4)*NCELL + xy;
      dst[0]       = ax;
      dst[NCELL]   = ay;
      dst[2*NCELL] = az;
      dst[3*NCELL] = aw;
    }
  }
}

extern "C" void kernel_launch(void* const* d_in, const int* in_sizes, int n_in,
                              void* d_out, int out_size, void* d_ws, size_t ws_size,
                              hipStream_t stream) {
  const float* feats  = (const float*)d_in[0];
  const float* itrans = (const float*)d_in[1];
  const float* iscale = (const float*)d_in[2];
  const float* l2i    = (const float*)d_in[3];
  float* out = (float*)d_out;

  k_geomz<<<NPTS/256, 256, 0, stream>>>(itrans, iscale, l2i, out); // 7,788 blocks
  k_alloc<<<NBLK, 1024, 0, stream>>>();                            // 254 blocks
  k_fill<<<NPTS/256, 256, 0, stream>>>();                          // 7,788 blocks
  k_gather<<<TOTBLK, 256, 0, stream>>>(feats, out);                // 2,048 blocks
}